// Round 3
// baseline (384.902 us; speedup 1.0000x reference)
//
#include <hip/hip_runtime.h>
#include <hip/hip_bf16.h>
#include <math.h>

#define BS   16
#define NQ   900
#define NCLS 1000
#define NT   100          // targets per batch (rows for LSA)
#define MQ   900          // queries (cols for LSA)
#define NCOL (BS * NT)    // 1600 total target columns
#define NSLOT 15          // ceil(MQ / 64)

// ---------------------------------------------------------------------------
// Kernel 1: per-row softmax stats (max, sum of exp) over 1000 classes.
// ---------------------------------------------------------------------------
__global__ __launch_bounds__(256) void rowstats_kernel(
    const float* __restrict__ logits, float* __restrict__ stats) {
  const int row = blockIdx.x;
  const float* x = logits + (size_t)row * NCLS;
  const int tid = threadIdx.x;
  const int wave = tid >> 6, lane = tid & 63;

  float lmax = -INFINITY;
  for (int j = tid; j < NCLS; j += 256) lmax = fmaxf(lmax, x[j]);
  for (int o = 32; o > 0; o >>= 1) lmax = fmaxf(lmax, __shfl_xor(lmax, o, 64));
  __shared__ float wmax[4];
  if (lane == 0) wmax[wave] = lmax;
  __syncthreads();
  const float rmax = fmaxf(fmaxf(wmax[0], wmax[1]), fmaxf(wmax[2], wmax[3]));

  float psum = 0.f;
  for (int j = tid; j < NCLS; j += 256) psum += expf(x[j] - rmax);
  for (int o = 32; o > 0; o >>= 1) psum += __shfl_xor(psum, o, 64);
  __shared__ float wsum[4];
  if (lane == 0) wsum[wave] = psum;
  __syncthreads();
  if (tid == 0) {
    stats[2 * row]     = rmax;
    stats[2 * row + 1] = wsum[0] + wsum[1] + wsum[2] + wsum[3];
  }
}

// ---------------------------------------------------------------------------
// Kernel 2: cost matrix Cm[b,q,col] = L1(bbox) - softmax_prob[tgt_id].
// Also scatters the per-batch diagonal block (transposed) into costT.
// ---------------------------------------------------------------------------
__global__ __launch_bounds__(256) void cost_kernel(
    const float* __restrict__ logits, const float* __restrict__ boxes,
    const int* __restrict__ ids, const float* __restrict__ tbox,
    const float* __restrict__ stats, float* __restrict__ C,
    float* __restrict__ costT, int id_stride) {
  const int row = blockIdx.x;              // 0..14399
  const int b = row / NQ;
  const int q = row - b * NQ;
  const float4 bb = *reinterpret_cast<const float4*>(boxes + (size_t)row * 4);
  const float rmax = stats[2 * row];
  const float rsum = stats[2 * row + 1];
  const float* lrow = logits + (size_t)row * NCLS;
  float* crow = C + (size_t)row * NCOL;
  const int jlo = b * NT;

  for (int j = threadIdx.x; j < NCOL; j += 256) {
    const int id = ids[(size_t)j * id_stride];
    const float4 tb = *reinterpret_cast<const float4*>(tbox + (size_t)j * 4);
    float d = fabsf(bb.x - tb.x);
    d += fabsf(bb.y - tb.y);
    d += fabsf(bb.z - tb.z);
    d += fabsf(bb.w - tb.w);
    const float p = expf(lrow[id] - rmax) / rsum;
    const float cost = d + (-p);
    crow[j] = cost;
    const int r = j - jlo;
    if ((unsigned)r < (unsigned)NT) {
      costT[((size_t)b * NT + r) * MQ + q] = cost;
    }
  }
}

// ---------------------------------------------------------------------------
// Kernel 3: Jonker-Volgenant LSA, bit-exact replica of the reference
// recursion (float64, first-index tie-break). ONE WAVE per batch; zero
// barriers (wave-synchronous); DPP argmin reduction; ping-pong row buffers.
// ---------------------------------------------------------------------------
union dbits { double d; int2 i; };

__device__ __forceinline__ void lexmin(double& av, int& aj, double bv, int bj) {
  if (bv < av || (bv == av && bj < aj)) { av = bv; aj = bj; }
}

template <int CTRL>
__device__ __forceinline__ void dpp_combine(double& bv, int& bj) {
  dbits x; x.d = bv;
  const int plo = __builtin_amdgcn_update_dpp(x.i.x, x.i.x, CTRL, 0xF, 0xF, false);
  const int phi = __builtin_amdgcn_update_dpp(x.i.y, x.i.y, CTRL, 0xF, 0xF, false);
  const int pj  = __builtin_amdgcn_update_dpp(bj,    bj,    CTRL, 0xF, 0xF, false);
  dbits pb; pb.i.x = plo; pb.i.y = phi;
  lexmin(bv, bj, pb.d, pj);
}

__global__ __launch_bounds__(64) void lsa_kernel(
    const float* __restrict__ costT, float* __restrict__ out_i,
    float* __restrict__ out_j) {
  const int b = blockIdx.x;
  const float* cost = costT + (size_t)b * NT * MQ;
  const int lane = threadIdx.x;
  const double DINF = __builtin_inf();

  __shared__ double u[NT + 1];
  __shared__ int p[MQ + 1];
  __shared__ int way[MQ + 1];
  __shared__ int cols[NT];
  __shared__ float warmbuf[256];

  double v[NSLOT], minv[NSLOT];
  float cfA[NSLOT], cfB[NSLOT];

  // register prefetch of the first pivot row (row 0, for i=1)
#pragma unroll
  for (int s = 0; s < NSLOT; ++s) {
    const int c = s * 64 + lane;
    cfA[s] = (c < MQ) ? cost[c] : 0.f;
  }

  // L2-warm: stream the whole 360 KB block through this XCD's L2 via
  // global_load_lds (no VGPR round-trip, no per-load consume stall).
  for (int t = 0; t < (NT * MQ) / 256; ++t) {
    __builtin_amdgcn_global_load_lds(
        (const __attribute__((address_space(1))) unsigned int*)
            (cost + t * 256 + lane * 4),
        (__attribute__((address_space(3))) unsigned int*)warmbuf, 16, 0, 0);
  }

#pragma unroll
  for (int s = 0; s < NSLOT; ++s) v[s] = 0.0;
  for (int j = lane; j <= MQ; j += 64) p[j] = 0;
  for (int i = lane; i <= NT; i += 64) u[i] = 0.0;

  for (int i = 1; i <= NT; ++i) {
#pragma unroll
    for (int s = 0; s < NSLOT; ++s) minv[s] = DINF;
    unsigned usedm = 0;
    if (lane == 0) p[0] = i;

    int j0 = 0;
    double ui0 = 0.0;   // u[i] == 0 for a fresh row (only path rows get updated)

    // One Dijkstra step: scan CUR's pivot row, pick argmin, prefetch the
    // next pivot row into NXT, apply potential updates. Returns false when
    // a free column was reached.
    auto iterate = [&](float (&CUR)[NSLOT], float (&NXT)[NSLOT]) -> bool {
      if (j0 > 0) {
        const int cz = j0 - 1;
        if (lane == (cz & 63)) usedm |= (1u << (cz >> 6));
      }
      // scan free columns; collect per-slot (minv, j) candidates
      double tv[NSLOT]; int tj[NSLOT];
#pragma unroll
      for (int s = 0; s < NSLOT; ++s) {
        const int c = s * 64 + lane;
        double mv = DINF; int mj = 0x7fffffff;
        if (c < MQ && !((usedm >> s) & 1u)) {
          const double cur = (double)CUR[s] - ui0 - v[s];
          if (cur < minv[s]) { minv[s] = cur; way[c + 1] = j0; }
          mv = minv[s]; mj = c + 1;
        }
        tv[s] = mv; tj[s] = mj;
      }
      // lexicographic min tree over the 15 slots (static indices)
#pragma unroll
      for (int st = 1; st < NSLOT; st <<= 1) {
#pragma unroll
        for (int s = 0; s + st < NSLOT; s += 2 * st)
          lexmin(tv[s], tj[s], tv[s + st], tj[s + st]);
      }
      double bestv = tv[0]; int bestj = tj[0];
      // wave argmin via DPP (result lands in lane 63)
      dpp_combine<0xB1>(bestv, bestj);   // quad_perm xor1
      dpp_combine<0x4E>(bestv, bestj);   // quad_perm xor2
      dpp_combine<0x114>(bestv, bestj);  // row_shr:4
      dpp_combine<0x118>(bestv, bestj);  // row_shr:8
      dpp_combine<0x142>(bestv, bestj);  // row_bcast15
      dpp_combine<0x143>(bestv, bestj);  // row_bcast31
      dbits rb; rb.d = bestv;
      dbits db;
      db.i.x = __builtin_amdgcn_readlane(rb.i.x, 63);
      db.i.y = __builtin_amdgcn_readlane(rb.i.y, 63);
      const int j1 = __builtin_amdgcn_readlane(bestj, 63);
      const double delta = db.d;

      const int pj1 = p[j1];
      const double unext = u[pj1];   // provably untouched by this iter's updates

      // prefetch next pivot row while updating potentials
      if (pj1 != 0) {
        const float* crow = cost + (size_t)(pj1 - 1) * MQ;
#pragma unroll
        for (int s = 0; s < NSLOT; ++s) {
          const int c = s * 64 + lane;
          NXT[s] = (c < MQ) ? crow[c] : 0.f;
        }
      }

      // potential updates (used cols map to distinct rows: race-free)
#pragma unroll
      for (int s = 0; s < NSLOT; ++s) {
        const int c = s * 64 + lane;
        if (c < MQ) {
          if ((usedm >> s) & 1u) {
            v[s] -= delta;
            u[p[c + 1]] += delta;
          } else {
            minv[s] -= delta;
          }
        }
      }
      if (lane == 0) u[i] += delta;   // virtual column 0 (p[0] == i)

      j0 = j1;
      ui0 = unext;
      return pj1 != 0;
    };

    while (true) {
      if (!iterate(cfA, cfB)) break;
      if (!iterate(cfB, cfA)) break;
    }

    // prefetch the NEXT row's initial pivot row (row i) into cfA,
    // overlapping with the serial augmentation walk.
    if (i < NT) {
      const float* crow = cost + (size_t)i * MQ;
#pragma unroll
      for (int s = 0; s < NSLOT; ++s) {
        const int c = s * 64 + lane;
        cfA[s] = (c < MQ) ? crow[c] : 0.f;
      }
    }

    // augment along the alternating path (serial, lane 0)
    if (lane == 0) {
      int ja = j0;
      while (ja != 0) { const int jb = way[ja]; p[ja] = p[jb]; ja = jb; }
    }
  }

  // extract assignment: cols[row] = column
  for (int j = lane + 1; j <= MQ; j += 64)
    if (p[j] > 0) cols[p[j] - 1] = j - 1;

  // order = argsort(cols); idx_i = cols[order], idx_j = order
  for (int r = lane; r < NT; r += 64) {
    const int c = cols[r];
    int rank = 0;
    for (int r2 = 0; r2 < NT; ++r2) rank += (cols[r2] < c);
    out_i[b * NT + rank] = (float)c;
    out_j[b * NT + rank] = (float)r;
  }
}

extern "C" void kernel_launch(void* const* d_in, const int* in_sizes, int n_in,
                              void* d_out, int out_size, void* d_ws,
                              size_t ws_size, hipStream_t stream) {
  const float* logits = (const float*)d_in[0];
  const float* boxes  = (const float*)d_in[1];
  const int*   ids    = (const int*)d_in[2];
  const float* tbox   = (const float*)d_in[3];

  float* C     = (float*)d_out;                      // 16*900*1600
  float* out_i = C + (size_t)BS * NQ * NCOL;         // 1600
  float* out_j = out_i + NCOL;                       // 1600

  float* stats = (float*)d_ws;                       // 2 * 14400 floats
  float* costT = stats + 2 * BS * NQ;                // 16*100*900 floats

  const int id_stride = (in_sizes[2] == 2 * NCOL) ? 2 : 1;

  rowstats_kernel<<<BS * NQ, 256, 0, stream>>>(logits, stats);
  cost_kernel<<<BS * NQ, 256, 0, stream>>>(logits, boxes, ids, tbox, stats, C,
                                           costT, id_stride);
  lsa_kernel<<<BS, 64, 0, stream>>>(costT, out_i, out_j);
}

// Round 5
// 332.647 us; speedup vs baseline: 1.1571x; 1.1571x over previous
//
#include <hip/hip_runtime.h>
#include <hip/hip_bf16.h>
#include <math.h>

#define BS   16
#define NQ   900
#define NCLS 1000
#define NT   100          // targets per batch (rows for LSA)
#define MQ   900          // queries (cols for LSA)
#define NCOL (BS * NT)    // 1600 total target columns
#define NSLOT 15          // ceil(MQ / 64)

// ---------------------------------------------------------------------------
// Kernel 1 (fused): per-row softmax stats + cost matrix. Logits row staged in
// LDS so the 57.6 MB logits array is read exactly once.
// ---------------------------------------------------------------------------
__global__ __launch_bounds__(256) void fusedcost_kernel(
    const float* __restrict__ logits, const float* __restrict__ boxes,
    const int* __restrict__ ids, const float* __restrict__ tbox,
    float* __restrict__ C, float* __restrict__ costT, int id_stride) {
  const int row = blockIdx.x;              // 0..14399
  const int b = row / NQ;
  const int q = row - b * NQ;
  const int tid = threadIdx.x, wave = tid >> 6, lane = tid & 63;

  __shared__ float lrow_s[NCLS];
  __shared__ float red[8];

  const float4* l4 = (const float4*)(logits + (size_t)row * NCLS);
  if (tid < NCLS / 4) ((float4*)lrow_s)[tid] = l4[tid];
  __syncthreads();

  float lmax = -INFINITY;
  for (int j = tid; j < NCLS; j += 256) lmax = fmaxf(lmax, lrow_s[j]);
  for (int o = 32; o > 0; o >>= 1) lmax = fmaxf(lmax, __shfl_xor(lmax, o, 64));
  if (lane == 0) red[wave] = lmax;
  __syncthreads();
  const float rmax = fmaxf(fmaxf(red[0], red[1]), fmaxf(red[2], red[3]));

  float psum = 0.f;
  for (int j = tid; j < NCLS; j += 256) psum += expf(lrow_s[j] - rmax);
  for (int o = 32; o > 0; o >>= 1) psum += __shfl_xor(psum, o, 64);
  if (lane == 0) red[4 + wave] = psum;
  __syncthreads();
  const float rsum = red[4] + red[5] + red[6] + red[7];

  const float4 bb = *reinterpret_cast<const float4*>(boxes + (size_t)row * 4);
  float* crow = C + (size_t)row * NCOL;
  const int jlo = b * NT;

  for (int j = tid; j < NCOL; j += 256) {
    const int id = ids[(size_t)j * id_stride];
    const float4 tb = *reinterpret_cast<const float4*>(tbox + (size_t)j * 4);
    float d = fabsf(bb.x - tb.x);
    d += fabsf(bb.y - tb.y);
    d += fabsf(bb.z - tb.z);
    d += fabsf(bb.w - tb.w);
    const float p = expf(lrow_s[id] - rmax) / rsum;
    const float cost = d + (-p);
    crow[j] = cost;
    const int r = j - jlo;
    if ((unsigned)r < (unsigned)NT) {
      costT[((size_t)b * NT + r) * MQ + q] = cost;
    }
  }
}

// ---------------------------------------------------------------------------
// Kernel 2: Jonker-Volgenant LSA, bit-exact replica of the reference
// recursion (float64, first-index tie-break). ONE WAVE per batch; zero
// barriers; DPP argmin; p packed into the reduce payload; u in registers.
// After each augmentation, jp is rebuilt from p[] in LDS (bounded, safe).
// ---------------------------------------------------------------------------
union dbits { double d; int2 i; };

__device__ __forceinline__ void lexmin(double& av, int& aj, double bv, int bj) {
  if (bv < av || (bv == av && bj < aj)) { av = bv; aj = bj; }
}

template <int CTRL>
__device__ __forceinline__ void dpp_combine(double& bv, int& bj) {
  dbits x; x.d = bv;
  const int plo = __builtin_amdgcn_update_dpp(x.i.x, x.i.x, CTRL, 0xF, 0xF, false);
  const int phi = __builtin_amdgcn_update_dpp(x.i.y, x.i.y, CTRL, 0xF, 0xF, false);
  const int pj  = __builtin_amdgcn_update_dpp(bj,    bj,    CTRL, 0xF, 0xF, false);
  dbits pb; pb.i.x = plo; pb.i.y = phi;
  lexmin(bv, bj, pb.d, pj);
}

__global__ __launch_bounds__(64, 1) void lsa_kernel(
    const float* __restrict__ costT, float* __restrict__ out_i,
    float* __restrict__ out_j) {
  const int b = blockIdx.x;
  const float* cost = costT + (size_t)b * NT * MQ;
  const int lane = threadIdx.x;
  const double DINF = __builtin_inf();
  const float FINF = __builtin_inff();

  __shared__ int p[MQ + 1];
  __shared__ int way[MQ + 1];
  __shared__ int cols[NT];

  double v[NSLOT], minv[NSLOT];
  float cfA[NSLOT], cfB[NSLOT], cfI[NSLOT];
  int jp[NSLOT];                 // (j << 7) | p[j]  for this lane's columns
  double u0 = 0.0, u1 = 0.0;     // u[lane+1], u[lane+65]
  int tm0 = 0, tm1 = 0;          // tree membership of owned rows

#pragma unroll
  for (int s = 0; s < NSLOT; ++s) {
    v[s] = 0.0;
    const int c = s * 64 + lane;
    jp[s] = (c + 1) << 7;                      // p[c+1] = 0
    cfA[s] = (c < MQ) ? cost[c] : FINF;        // row 0 for i=1
  }
  for (int j = lane; j <= MQ; j += 64) p[j] = 0;

  for (int i = 1; i <= NT; ++i) {
    unsigned usedm = 0;
    tm0 = 0; tm1 = 0;
#pragma unroll
    for (int s = 0; s < NSLOT; ++s) minv[s] = DINF;
    if (lane == 0) p[0] = i;

    // prefetch the NEXT Dijkstra's initial pivot row (0-based row i):
    // hides its compulsory HBM/L2 latency under this whole Dijkstra.
    if (i < NT) {
      const float* crow = cost + (size_t)i * MQ;
#pragma unroll
      for (int s = 0; s < NSLOT; ++s) {
        const int c = s * 64 + lane;
        cfI[s] = (c < MQ) ? crow[c] : FINF;
      }
    }

    int j0 = 0;
    int i0 = i;
    double ui0 = 0.0;            // u[i] == 0 for a fresh row

    auto iterate = [&](float (&CUR)[NSLOT], float (&NXT)[NSLOT]) -> bool {
      // column j0 becomes used (j0 == 0 is the virtual column)
      if (j0 > 0) {
        const int cz = j0 - 1;
        const bool own = (lane == (cz & 63));
        usedm |= own ? (1u << (cz >> 6)) : 0u;
      }
      // row i0 joins the tree (receives +delta each iteration from now on)
      {
        const int ri = i0 - 1;
        tm0 |= (lane == ri) ? 1 : 0;
        tm1 |= (lane == (ri - 64)) ? 1 : 0;
      }

      // scan: relax free columns; used/pad columns made inert via +INF
      // (adds exactly 0.0 to free ones -> bit-identical to the reference)
      double tv[NSLOT]; int tj[NSLOT];
#pragma unroll
      for (int s = 0; s < NSLOT; ++s) {
        const bool us = (usedm >> s) & 1u;
        const double pw = us ? DINF : 0.0;
        const double cur = ((double)CUR[s] - ui0 - v[s]) + pw;
        if (cur < minv[s]) { minv[s] = cur; way[s * 64 + lane + 1] = j0; }
        tv[s] = minv[s] + pw;
        tj[s] = jp[s];
      }
      // lexicographic min tree over slots (ascending j within lane)
#pragma unroll
      for (int st = 1; st < NSLOT; st <<= 1) {
#pragma unroll
        for (int s = 0; s + st < NSLOT; s += 2 * st)
          lexmin(tv[s], tj[s], tv[s + st], tj[s + st]);
      }
      double bestv = tv[0]; int bestj = tj[0];
      dpp_combine<0xB1>(bestv, bestj);   // quad_perm xor1
      dpp_combine<0x4E>(bestv, bestj);   // quad_perm xor2
      dpp_combine<0x114>(bestv, bestj);  // row_shr:4
      dpp_combine<0x118>(bestv, bestj);  // row_shr:8
      dpp_combine<0x142>(bestv, bestj);  // row_bcast15
      dpp_combine<0x143>(bestv, bestj);  // row_bcast31
      dbits rb; rb.d = bestv;
      dbits db;
      db.i.x = __builtin_amdgcn_readlane(rb.i.x, 63);
      db.i.y = __builtin_amdgcn_readlane(rb.i.y, 63);
      const int jpw = __builtin_amdgcn_readlane(bestj, 63);
      const double delta = db.d;
      const int j1 = jpw >> 7;
      const int pj1 = jpw & 127;         // p[j1], carried through the reduce

      // prefetch next pivot row IMMEDIATELY (no LDS read needed for p[j1])
      if (pj1 != 0) {
        const float* crow = cost + (size_t)(pj1 - 1) * MQ;
#pragma unroll
        for (int s = 0; s < NSLOT; ++s) {
          const int c = s * 64 + lane;
          NXT[s] = (c < MQ) ? crow[c] : FINF;
        }
      }
      // u[pj1] from distributed registers (untouched by this iter's update:
      // row p[j1] is not yet in the tree -- matches the reference's read)
      double unext = 0.0;
      if (pj1 != 0) {
        const int r = pj1 - 1;
        dbits t; t.d = (r < 64) ? u0 : u1;
        dbits o;
        o.i.x = __builtin_amdgcn_readlane(t.i.x, r & 63);
        o.i.y = __builtin_amdgcn_readlane(t.i.y, r & 63);
        unext = o.d;
      }

      // potential updates
      u0 += tm0 ? delta : 0.0;
      u1 += tm1 ? delta : 0.0;
#pragma unroll
      for (int s = 0; s < NSLOT; ++s) {
        const bool us = (usedm >> s) & 1u;
        v[s]    -= us ? delta : 0.0;
        minv[s] -= us ? 0.0 : delta;
      }

      j0 = j1; i0 = pj1; ui0 = unext;
      return pj1 != 0;
    };

    while (true) {
      if (!iterate(cfA, cfB)) break;
      if (!iterate(cfB, cfA)) break;
    }

    // augment along the alternating path (serial, lane 0)
    if (lane == 0) {
      int ja = j0;
      while (ja != 0) { const int jb = way[ja]; p[ja] = p[jb]; ja = jb; }
    }
    // rebuild the packed jp registers from p (bounded, conflict-free reads;
    // wave-synchronous LDS read-after-write within one wave)
#pragma unroll
    for (int s = 0; s < NSLOT; ++s) {
      const int c = s * 64 + lane;
      if (c < MQ) jp[s] = ((c + 1) << 7) | p[c + 1];
    }
    // rotate in the prefetched initial row for Dijkstra i+1
    if (i < NT) {
#pragma unroll
      for (int s = 0; s < NSLOT; ++s) cfA[s] = cfI[s];
    }
  }

  // extract assignment: cols[row] = column
  for (int j = lane + 1; j <= MQ; j += 64)
    if (p[j] > 0) cols[p[j] - 1] = j - 1;

  // order = argsort(cols); idx_i = cols[order], idx_j = order
  for (int r = lane; r < NT; r += 64) {
    const int c = cols[r];
    int rank = 0;
    for (int r2 = 0; r2 < NT; ++r2) rank += (cols[r2] < c);
    out_i[b * NT + rank] = (float)c;
    out_j[b * NT + rank] = (float)r;
  }
}

extern "C" void kernel_launch(void* const* d_in, const int* in_sizes, int n_in,
                              void* d_out, int out_size, void* d_ws,
                              size_t ws_size, hipStream_t stream) {
  const float* logits = (const float*)d_in[0];
  const float* boxes  = (const float*)d_in[1];
  const int*   ids    = (const int*)d_in[2];
  const float* tbox   = (const float*)d_in[3];

  float* C     = (float*)d_out;                      // 16*900*1600
  float* out_i = C + (size_t)BS * NQ * NCOL;         // 1600
  float* out_j = out_i + NCOL;                       // 1600

  float* costT = (float*)d_ws;                       // 16*100*900 floats

  const int id_stride = (in_sizes[2] == 2 * NCOL) ? 2 : 1;

  fusedcost_kernel<<<BS * NQ, 256, 0, stream>>>(logits, boxes, ids, tbox, C,
                                                costT, id_stride);
  lsa_kernel<<<BS, 64, 0, stream>>>(costT, out_i, out_j);
}

// Round 6
// 277.430 us; speedup vs baseline: 1.3874x; 1.1990x over previous
//
#include <hip/hip_runtime.h>
#include <hip/hip_bf16.h>
#include <math.h>

#define BS   16
#define NQ   900
#define NCLS 1000
#define NT   100          // targets per batch (rows for LSA)
#define MQ   900          // queries (cols for LSA)
#define NCOL (BS * NT)    // 1600 total target columns
#define NSLOT 15          // ceil(MQ / 64)

// ---------------------------------------------------------------------------
// Kernel 1 (fused): per-row softmax stats + cost matrix. Logits row staged in
// LDS so the 57.6 MB logits array is read exactly once.
// ---------------------------------------------------------------------------
__global__ __launch_bounds__(256) void fusedcost_kernel(
    const float* __restrict__ logits, const float* __restrict__ boxes,
    const int* __restrict__ ids, const float* __restrict__ tbox,
    float* __restrict__ C, float* __restrict__ costT, int id_stride) {
  const int row = blockIdx.x;              // 0..14399
  const int b = row / NQ;
  const int q = row - b * NQ;
  const int tid = threadIdx.x, wave = tid >> 6, lane = tid & 63;

  __shared__ float lrow_s[NCLS];
  __shared__ float red[8];

  const float4* l4 = (const float4*)(logits + (size_t)row * NCLS);
  if (tid < NCLS / 4) ((float4*)lrow_s)[tid] = l4[tid];
  __syncthreads();

  float lmax = -INFINITY;
  for (int j = tid; j < NCLS; j += 256) lmax = fmaxf(lmax, lrow_s[j]);
  for (int o = 32; o > 0; o >>= 1) lmax = fmaxf(lmax, __shfl_xor(lmax, o, 64));
  if (lane == 0) red[wave] = lmax;
  __syncthreads();
  const float rmax = fmaxf(fmaxf(red[0], red[1]), fmaxf(red[2], red[3]));

  float psum = 0.f;
  for (int j = tid; j < NCLS; j += 256) psum += expf(lrow_s[j] - rmax);
  for (int o = 32; o > 0; o >>= 1) psum += __shfl_xor(psum, o, 64);
  if (lane == 0) red[4 + wave] = psum;
  __syncthreads();
  const float rsum = red[4] + red[5] + red[6] + red[7];

  const float4 bb = *reinterpret_cast<const float4*>(boxes + (size_t)row * 4);
  float* crow = C + (size_t)row * NCOL;
  const int jlo = b * NT;

  for (int j = tid; j < NCOL; j += 256) {
    const int id = ids[(size_t)j * id_stride];
    const float4 tb = *reinterpret_cast<const float4*>(tbox + (size_t)j * 4);
    float d = fabsf(bb.x - tb.x);
    d += fabsf(bb.y - tb.y);
    d += fabsf(bb.z - tb.z);
    d += fabsf(bb.w - tb.w);
    const float p = expf(lrow_s[id] - rmax) / rsum;
    const float cost = d + (-p);
    crow[j] = cost;
    const int r = j - jlo;
    if ((unsigned)r < (unsigned)NT) {
      costT[((size_t)b * NT + r) * MQ + q] = cost;
    }
  }
}

// ---------------------------------------------------------------------------
// Kernel 2: Jonker-Volgenant LSA in f32 with packed u64 sort keys.
// key = (bits(minv+D) << 17) | (j << 7) | p[j]; minv >= 0 (dual feasibility)
// makes f32 bits monotonic as unsigned, so u64-min == lexicographic
// (value, j) min with first-index tie-break, and carries p[j1] for free.
// D-offset removes the per-iteration "minv -= delta" loop; keys are cached
// and only rebuilt on relax. ONE WAVE per batch; zero barriers.
// ---------------------------------------------------------------------------
template <int CTRL>
__device__ __forceinline__ unsigned long long dpp_u64(unsigned long long x) {
  const int lo = (int)(unsigned)x;
  const int hi = (int)(unsigned)(x >> 32);
  const int plo = __builtin_amdgcn_update_dpp(lo, lo, CTRL, 0xF, 0xF, false);
  const int phi = __builtin_amdgcn_update_dpp(hi, hi, CTRL, 0xF, 0xF, false);
  return ((unsigned long long)(unsigned)phi << 32) | (unsigned)plo;
}

template <int CTRL>
__device__ __forceinline__ void dpp_kmin(unsigned long long& k) {
  const unsigned long long o = dpp_u64<CTRL>(k);
  k = (o < k) ? o : k;
}

__global__ __launch_bounds__(64, 1) void lsa_kernel(
    const float* __restrict__ costT, float* __restrict__ out_i,
    float* __restrict__ out_j) {
  const int b = blockIdx.x;
  const float* cost = costT + (size_t)b * NT * MQ;
  const int lane = threadIdx.x;
  const float FINF = __builtin_inff();
  const unsigned long long KMAX = ~0ull;

  __shared__ int p[MQ + 1];
  __shared__ int way[MQ + 65];   // [901..964] absorb pad-column writes; [0] dummy
  __shared__ int cols[NT];

  float v[NSLOT];
  unsigned long long K[NSLOT];   // cached keys of (minv + D, j, p[j])
  float cfA[NSLOT], cfB[NSLOT], cfI[NSLOT];
  int jp[NSLOT];                 // (j << 7) | p[j] for this lane's columns
  float u0 = 0.f, u1 = 0.f;      // u[lane+1], u[lane+65]

#pragma unroll
  for (int s = 0; s < NSLOT; ++s) {
    v[s] = 0.f;
    const int c = s * 64 + lane;
    jp[s] = (c + 1) << 7;                      // p[c+1] = 0
    cfA[s] = (c < MQ) ? cost[c] : FINF;        // row 0 for i=1
  }
  for (int j = lane; j <= MQ; j += 64) p[j] = 0;

  for (int i = 1; i <= NT; ++i) {
    unsigned usedm = 0;
    int tm0 = 0, tm1 = 0;        // tree membership of owned rows
    float D = 0.f;               // accumulated delta offset
#pragma unroll
    for (int s = 0; s < NSLOT; ++s) K[s] = KMAX;
    if (lane == 0) p[0] = i;

    // prefetch the NEXT Dijkstra's initial pivot row (0-based row i)
    if (i < NT) {
      const float* crow = cost + (size_t)i * MQ;
#pragma unroll
      for (int s = 0; s < NSLOT; ++s) {
        const int c = s * 64 + lane;
        cfI[s] = (c < MQ) ? crow[c] : FINF;
      }
    }

    int j0 = 0;
    int i0 = i;
    float ui0 = 0.f;             // u[i] == 0 for a fresh row

    auto iterate = [&](float (&CUR)[NSLOT], float (&NXT)[NSLOT]) -> bool {
      // column j0 becomes used (j0 == 0 is the virtual column)
      if (j0 > 0) {
        const int cz = j0 - 1;
        const bool own = (lane == (cz & 63));
        usedm |= own ? (1u << (cz >> 6)) : 0u;
      }
      // row i0 joins the tree (receives +delta from this iteration on)
      {
        const int ri = i0 - 1;
        tm0 |= (lane == ri) ? 1 : 0;
        tm1 |= (lane == (ri - 64)) ? 1 : 0;
      }

      const float a = ui0 - D;   // scan in offset space: rel = cur + D
      unsigned long long tk[NSLOT];
#pragma unroll
      for (int s = 0; s < NSLOT; ++s) {
        const bool us = (usedm >> s) & 1u;
        const float pen = us ? FINF : 0.f;     // used cols -> rel = +INF
        const float rel = fmaxf(CUR[s] - a - v[s], 0.f) + pen;
        const unsigned rb = __float_as_uint(rel);
        const unsigned long long rk =
            ((unsigned long long)(rb >> 15) << 32) |
            ((rb << 17) | (unsigned)jp[s]);
        // relax vs STORED key; used cols: rk(INF) >= stale K -> no relax,
        // so way[] of tree columns stays frozen (augment path integrity).
        const bool upd = rk < K[s];
        way[upd ? (s * 64 + lane + 1) : 0] = j0;
        K[s] = upd ? rk : K[s];
        tk[s] = us ? KMAX : K[s];              // tree never picks used cols
      }
      // u64 min tree over slots, then wave min via DPP (lands in lane 63)
#pragma unroll
      for (int st = 1; st < NSLOT; st <<= 1) {
#pragma unroll
        for (int s = 0; s + st < NSLOT; s += 2 * st)
          tk[s] = (tk[s + st] < tk[s]) ? tk[s + st] : tk[s];
      }
      unsigned long long bk = tk[0];
      dpp_kmin<0xB1>(bk);    // quad_perm xor1
      dpp_kmin<0x4E>(bk);    // quad_perm xor2
      dpp_kmin<0x114>(bk);   // row_shr:4
      dpp_kmin<0x118>(bk);   // row_shr:8
      dpp_kmin<0x142>(bk);   // row_bcast15
      dpp_kmin<0x143>(bk);   // row_bcast31
      const unsigned whi =
          (unsigned)__builtin_amdgcn_readlane((int)(unsigned)(bk >> 32), 63);
      const unsigned wlo =
          (unsigned)__builtin_amdgcn_readlane((int)(unsigned)bk, 63);
      const float Dnew = __uint_as_float((whi << 15) | (wlo >> 17));
      const int j1 = (int)((wlo >> 7) & 0x3FFu);
      const int pj1 = (int)(wlo & 127u);       // p[j1], carried in the key

      // prefetch next pivot row immediately
      if (pj1 != 0) {
        const float* crow = cost + (size_t)(pj1 - 1) * MQ;
#pragma unroll
        for (int s = 0; s < NSLOT; ++s) {
          const int c = s * 64 + lane;
          NXT[s] = (c < MQ) ? crow[c] : FINF;
        }
      }
      // u[pj1] from distributed registers (row not yet in tree -> exact)
      float unext = 0.f;
      if (pj1 != 0) {
        const int r = pj1 - 1;
        const float uu = (r < 64) ? u0 : u1;
        unext = __uint_as_float(
            (unsigned)__builtin_amdgcn_readlane((int)__float_as_uint(uu),
                                                r & 63));
      }

      const float delta = Dnew - D;
      D = Dnew;                 // "minv[free] -= delta" absorbed by offset
      u0 += tm0 ? delta : 0.f;
      u1 += tm1 ? delta : 0.f;
#pragma unroll
      for (int s = 0; s < NSLOT; ++s) {
        const bool us = (usedm >> s) & 1u;
        v[s] -= us ? delta : 0.f;
      }

      j0 = j1; i0 = pj1; ui0 = unext;
      return pj1 != 0;
    };

    while (true) {
      if (!iterate(cfA, cfB)) break;
      if (!iterate(cfB, cfA)) break;
    }

    // augment along the alternating path (serial, lane 0)
    if (lane == 0) {
      int ja = j0;
      while (ja != 0) { const int jb = way[ja]; p[ja] = p[jb]; ja = jb; }
    }
    // rebuild the packed jp registers from p (wave-synchronous LDS RAW)
#pragma unroll
    for (int s = 0; s < NSLOT; ++s) {
      const int c = s * 64 + lane;
      if (c < MQ) jp[s] = ((c + 1) << 7) | p[c + 1];
    }
    // rotate in the prefetched initial row for Dijkstra i+1
    if (i < NT) {
#pragma unroll
      for (int s = 0; s < NSLOT; ++s) cfA[s] = cfI[s];
    }
  }

  // extract assignment: cols[row] = column
  for (int j = lane + 1; j <= MQ; j += 64)
    if (p[j] > 0) cols[p[j] - 1] = j - 1;

  // order = argsort(cols); idx_i = cols[order], idx_j = order
  for (int r = lane; r < NT; r += 64) {
    const int c = cols[r];
    int rank = 0;
    for (int r2 = 0; r2 < NT; ++r2) rank += (cols[r2] < c);
    out_i[b * NT + rank] = (float)c;
    out_j[b * NT + rank] = (float)r;
  }
}

extern "C" void kernel_launch(void* const* d_in, const int* in_sizes, int n_in,
                              void* d_out, int out_size, void* d_ws,
                              size_t ws_size, hipStream_t stream) {
  const float* logits = (const float*)d_in[0];
  const float* boxes  = (const float*)d_in[1];
  const int*   ids    = (const int*)d_in[2];
  const float* tbox   = (const float*)d_in[3];

  float* C     = (float*)d_out;                      // 16*900*1600
  float* out_i = C + (size_t)BS * NQ * NCOL;         // 1600
  float* out_j = out_i + NCOL;                       // 1600

  float* costT = (float*)d_ws;                       // 16*100*900 floats

  const int id_stride = (in_sizes[2] == 2 * NCOL) ? 2 : 1;

  fusedcost_kernel<<<BS * NQ, 256, 0, stream>>>(logits, boxes, ids, tbox, C,
                                                costT, id_stride);
  lsa_kernel<<<BS, 64, 0, stream>>>(costT, out_i, out_j);
}

// Round 7
// 209.444 us; speedup vs baseline: 1.8377x; 1.3246x over previous
//
#include <hip/hip_runtime.h>
#include <hip/hip_bf16.h>
#include <math.h>

#define BS   16
#define NQ   900
#define NCLS 1000
#define NT   100          // targets per batch (rows for LSA)
#define MQ   900          // queries (cols for LSA)
#define NCOL (BS * NT)    // 1600 total target columns
#define NSLOT 15          // ceil(MQ / 64)

// ---------------------------------------------------------------------------
// Kernel A: softmax stats + the transposed diagonal cost block (costT) only.
// Small (~15us) so the LSA can start ASAP; the big C write overlaps LSA.
// ---------------------------------------------------------------------------
__global__ __launch_bounds__(256) void statcost_kernel(
    const float* __restrict__ logits, const float* __restrict__ boxes,
    const int* __restrict__ ids, const float* __restrict__ tbox,
    float* __restrict__ stats, float* __restrict__ costT, int id_stride) {
  const int row = blockIdx.x;              // 0..14399
  const int b = row / NQ;
  const int q = row - b * NQ;
  const int tid = threadIdx.x, wave = tid >> 6, lane = tid & 63;

  __shared__ float lrow_s[NCLS];
  __shared__ float red[8];

  const float4* l4 = (const float4*)(logits + (size_t)row * NCLS);
  if (tid < NCLS / 4) ((float4*)lrow_s)[tid] = l4[tid];
  __syncthreads();

  float lmax = -INFINITY;
  for (int j = tid; j < NCLS; j += 256) lmax = fmaxf(lmax, lrow_s[j]);
  for (int o = 32; o > 0; o >>= 1) lmax = fmaxf(lmax, __shfl_xor(lmax, o, 64));
  if (lane == 0) red[wave] = lmax;
  __syncthreads();
  const float rmax = fmaxf(fmaxf(red[0], red[1]), fmaxf(red[2], red[3]));

  float psum = 0.f;
  for (int j = tid; j < NCLS; j += 256) psum += expf(lrow_s[j] - rmax);
  for (int o = 32; o > 0; o >>= 1) psum += __shfl_xor(psum, o, 64);
  if (lane == 0) red[4 + wave] = psum;
  __syncthreads();
  const float rsum = red[4] + red[5] + red[6] + red[7];
  if (tid == 0) { stats[2 * row] = rmax; stats[2 * row + 1] = rsum; }

  const float4 bb = *reinterpret_cast<const float4*>(boxes + (size_t)row * 4);
  for (int r = tid; r < NT; r += 256) {
    const int j = b * NT + r;
    const int id = ids[(size_t)j * id_stride];
    const float4 tb = *reinterpret_cast<const float4*>(tbox + (size_t)j * 4);
    float d = fabsf(bb.x - tb.x);
    d += fabsf(bb.y - tb.y);
    d += fabsf(bb.z - tb.z);
    d += fabsf(bb.w - tb.w);
    const float pr = expf(lrow_s[id] - rmax) / rsum;
    costT[((size_t)b * NT + r) * MQ + q] = d - pr;
  }
}

// ---------------------------------------------------------------------------
// Main kernel: blocks 0..15 run the JV LSA (one wave per batch, zero
// barriers); blocks 16.. write the full C matrix using the precomputed
// stats — that work overlaps the latency-bound LSA on the idle CUs.
// ---------------------------------------------------------------------------
__device__ __forceinline__ unsigned umin32(unsigned a, unsigned b) {
  return a < b ? a : b;
}

template <int CTRL>
__device__ __forceinline__ unsigned dpp_min_u32(unsigned x) {
  const unsigned o = (unsigned)__builtin_amdgcn_update_dpp(
      (int)x, (int)x, CTRL, 0xF, 0xF, false);
  return o < x ? o : x;
}

__global__ __launch_bounds__(256) void main_kernel(
    const float* __restrict__ logits, const float* __restrict__ boxes,
    const int* __restrict__ ids, const float* __restrict__ tbox,
    const float* __restrict__ stats, const float* __restrict__ costT,
    float* __restrict__ C, float* __restrict__ out_i,
    float* __restrict__ out_j, int id_stride) {
  __shared__ float lrow_s[NCLS];
  __shared__ int p[MQ + 1];
  __shared__ int way[MQ + 65];   // [901..964] absorb pad writes; [0] dummy
  __shared__ int cols[NT];

  if (blockIdx.x >= BS) {
    // ---------------- C-matrix path (overlaps LSA) ----------------
    const int row = blockIdx.x - BS;
    const int b = row / NQ;
    const int tid = threadIdx.x;
    const float4* l4 = (const float4*)(logits + (size_t)row * NCLS);
    if (tid < NCLS / 4) ((float4*)lrow_s)[tid] = l4[tid];
    __syncthreads();
    const float rmax = stats[2 * row];
    const float rsum = stats[2 * row + 1];
    const float4 bb = *reinterpret_cast<const float4*>(boxes + (size_t)row * 4);
    float* crow = C + (size_t)row * NCOL;
    for (int j = tid; j < NCOL; j += 256) {
      const int id = ids[(size_t)j * id_stride];
      const float4 tb = *reinterpret_cast<const float4*>(tbox + (size_t)j * 4);
      float d = fabsf(bb.x - tb.x);
      d += fabsf(bb.y - tb.y);
      d += fabsf(bb.z - tb.z);
      d += fabsf(bb.w - tb.w);
      crow[j] = d - expf(lrow_s[id] - rmax) / rsum;
    }
    return;
  }

  // ---------------- LSA path: one wave per batch ----------------
  if (threadIdx.x >= 64) return;
  const int b = blockIdx.x;
  const float* cost = costT + (size_t)b * NT * MQ;
  const int lane = threadIdx.x;
  const float FINF = __builtin_inff();
  const unsigned UMAX = 0xFFFFFFFFu;
  const unsigned UINFB = 0x7F800000u;    // +inf f32 bits

  float v[NSLOT];
  unsigned V32[NSLOT];           // stored (minv + D) as f32 bits; frozen on use
  float cfA[NSLOT], cfB[NSLOT], cfI[NSLOT];
  int jp[NSLOT];                 // (j << 7) | p[j] for this lane's columns
  float u0 = 0.f, u1 = 0.f;      // u[lane+1], u[lane+65]

#pragma unroll
  for (int s = 0; s < NSLOT; ++s) {
    v[s] = 0.f;
    const int c = s * 64 + lane;
    jp[s] = (c + 1) << 7;                      // p[c+1] = 0
    cfA[s] = (c < MQ) ? cost[c] : FINF;        // row 0 for i=1
  }
  for (int j = lane; j <= MQ; j += 64) p[j] = 0;

  for (int i = 1; i <= NT; ++i) {
    // pad columns (c >= MQ, slot 14 lanes >= 4) are permanently "used"
    unsigned usedm = (lane >= MQ - 14 * 64) ? (1u << 14) : 0u;
    int tm0 = 0, tm1 = 0;        // tree membership of owned rows
    float D = 0.f;               // accumulated delta offset
#pragma unroll
    for (int s = 0; s < NSLOT; ++s) V32[s] = UINFB;
    if (lane == 0) p[0] = i;

    // prefetch the NEXT Dijkstra's initial pivot row (0-based row i)
    if (i < NT) {
      const float* crow = cost + (size_t)i * MQ;
#pragma unroll
      for (int s = 0; s < NSLOT; ++s) {
        const int c = s * 64 + lane;
        cfI[s] = (c < MQ) ? crow[c] : FINF;
      }
    }

    int j0 = 0;
    int i0 = i;
    float ui0 = 0.f;             // u[i] == 0 for a fresh row

    auto iterate = [&](float (&CUR)[NSLOT], float (&NXT)[NSLOT]) -> bool {
      // column j0 becomes used (j0 == 0 is the virtual column)
      if (j0 > 0) {
        const int cz = j0 - 1;
        const bool own = (lane == (cz & 63));
        usedm |= own ? (1u << (cz >> 6)) : 0u;
      }
      // row i0 joins the tree (receives +delta from this iteration on)
      {
        const int ri = i0 - 1;
        tm0 |= (lane == ri) ? 1 : 0;
        tm1 |= (lane == (ri - 64)) ? 1 : 0;
      }

      const float a = ui0 - D;   // scan in offset space: rel = cur + D
      unsigned tv[NSLOT];
#pragma unroll
      for (int s = 0; s < NSLOT; ++s) {
        const bool us = (usedm >> s) & 1u;
        const float rel = fmaxf(CUR[s] - a - v[s], 0.f);
        const unsigned rb = __float_as_uint(rel);
        const unsigned rbg = us ? UMAX : rb;   // used cols never relax
        const bool upd = rbg < V32[s];
        way[upd ? (s * 64 + lane + 1) : 0] = j0;
        V32[s] = upd ? rbg : V32[s];
        tv[s] = us ? UMAX : V32[s];            // tree never picks used cols
      }
      // phase 1: value-only u32 min (slot tree + DPP), broadcast via SGPR
      unsigned m[NSLOT];
#pragma unroll
      for (int s = 0; s < NSLOT; ++s) m[s] = tv[s];
#pragma unroll
      for (int st = 1; st < NSLOT; st <<= 1) {
#pragma unroll
        for (int s = 0; s + st < NSLOT; s += 2 * st)
          m[s] = umin32(m[s], m[s + st]);
      }
      unsigned mm = m[0];
      mm = dpp_min_u32<0xB1>(mm);    // quad_perm xor1
      mm = dpp_min_u32<0x4E>(mm);    // quad_perm xor2
      mm = dpp_min_u32<0x114>(mm);   // row_shr:4
      mm = dpp_min_u32<0x118>(mm);   // row_shr:8
      mm = dpp_min_u32<0x142>(mm);   // row_bcast15
      mm = dpp_min_u32<0x143>(mm);   // row_bcast31
      const unsigned s_best =
          (unsigned)__builtin_amdgcn_readlane((int)mm, 63);
      const float Dnew = __uint_as_float(s_best);

      // phase 2: first-index tie-break — min over (j<<7|p) of candidates
      unsigned cj[NSLOT];
#pragma unroll
      for (int s = 0; s < NSLOT; ++s)
        cj[s] = (tv[s] == s_best) ? (unsigned)jp[s] : UMAX;
#pragma unroll
      for (int st = 1; st < NSLOT; st <<= 1) {
#pragma unroll
        for (int s = 0; s + st < NSLOT; s += 2 * st)
          cj[s] = umin32(cj[s], cj[s + st]);
      }
      unsigned cc = cj[0];
      cc = dpp_min_u32<0xB1>(cc);
      cc = dpp_min_u32<0x4E>(cc);
      cc = dpp_min_u32<0x114>(cc);
      cc = dpp_min_u32<0x118>(cc);
      cc = dpp_min_u32<0x142>(cc);
      cc = dpp_min_u32<0x143>(cc);
      const unsigned jpw = (unsigned)__builtin_amdgcn_readlane((int)cc, 63);
      const int j1 = (int)(jpw >> 7);
      const int pj1 = (int)(jpw & 127u);       // p[j1], carried in the key

      // prefetch next pivot row immediately
      if (pj1 != 0) {
        const float* crow = cost + (size_t)(pj1 - 1) * MQ;
#pragma unroll
        for (int s = 0; s < NSLOT; ++s) {
          const int c = s * 64 + lane;
          NXT[s] = (c < MQ) ? crow[c] : FINF;
        }
      }
      // u[pj1] from distributed registers (row not yet in tree -> exact)
      float unext = 0.f;
      if (pj1 != 0) {
        const int r = pj1 - 1;
        const float uu = (r < 64) ? u0 : u1;
        unext = __uint_as_float(
            (unsigned)__builtin_amdgcn_readlane((int)__float_as_uint(uu),
                                                r & 63));
      }

      const float delta = Dnew - D;
      D = Dnew;                  // minv/v updates absorbed by the offset
      u0 += tm0 ? delta : 0.f;
      u1 += tm1 ? delta : 0.f;

      j0 = j1; i0 = pj1; ui0 = unext;
      return pj1 != 0;
    };

    while (true) {
      if (!iterate(cfA, cfB)) break;
      if (!iterate(cfB, cfA)) break;
    }

    // deferred v fixup: a used column's use-time offset D_use equals its
    // frozen stored value V32; v_final = v_start - (D_end - D_use).
    {
      const float Dend = D;
#pragma unroll
      for (int s = 0; s < NSLOT; ++s) {
        const int c = s * 64 + lane;
        const bool us = (usedm >> s) & 1u;
        const float dv = __uint_as_float(V32[s]) - Dend;
        v[s] += (us && c < MQ) ? dv : 0.f;
      }
    }

    // augment along the alternating path (serial, lane 0)
    if (lane == 0) {
      int ja = j0;
      while (ja != 0) { const int jb = way[ja]; p[ja] = p[jb]; ja = jb; }
    }
    // rebuild the packed jp registers from p (wave-synchronous LDS RAW)
#pragma unroll
    for (int s = 0; s < NSLOT; ++s) {
      const int c = s * 64 + lane;
      if (c < MQ) jp[s] = ((c + 1) << 7) | p[c + 1];
    }
    // rotate in the prefetched initial row for Dijkstra i+1
    if (i < NT) {
#pragma unroll
      for (int s = 0; s < NSLOT; ++s) cfA[s] = cfI[s];
    }
  }

  // extract assignment: cols[row] = column
  for (int j = lane + 1; j <= MQ; j += 64)
    if (p[j] > 0) cols[p[j] - 1] = j - 1;

  // order = argsort(cols); idx_i = cols[order], idx_j = order
  for (int r = lane; r < NT; r += 64) {
    const int c = cols[r];
    int rank = 0;
    for (int r2 = 0; r2 < NT; ++r2) rank += (cols[r2] < c);
    out_i[b * NT + rank] = (float)c;
    out_j[b * NT + rank] = (float)r;
  }
}

extern "C" void kernel_launch(void* const* d_in, const int* in_sizes, int n_in,
                              void* d_out, int out_size, void* d_ws,
                              size_t ws_size, hipStream_t stream) {
  const float* logits = (const float*)d_in[0];
  const float* boxes  = (const float*)d_in[1];
  const int*   ids    = (const int*)d_in[2];
  const float* tbox   = (const float*)d_in[3];

  float* C     = (float*)d_out;                      // 16*900*1600
  float* out_i = C + (size_t)BS * NQ * NCOL;         // 1600
  float* out_j = out_i + NCOL;                       // 1600

  float* costT = (float*)d_ws;                       // 16*100*900 floats
  float* stats = costT + (size_t)BS * NT * MQ;       // 2 * 14400 floats

  const int id_stride = (in_sizes[2] == 2 * NCOL) ? 2 : 1;

  statcost_kernel<<<BS * NQ, 256, 0, stream>>>(logits, boxes, ids, tbox,
                                               stats, costT, id_stride);
  main_kernel<<<BS * NQ + BS, 256, 0, stream>>>(logits, boxes, ids, tbox,
                                                stats, costT, C, out_i, out_j,
                                                id_stride);
}